// Round 2
// baseline (244.292 us; speedup 1.0000x reference)
//
#include <hip/hip_runtime.h>
#include <math.h>

#define S 128
#define KA 25
#define KL 25
#define PATCH 625
#define FEAT 1250
#define PI_F 3.14159265358979323846f
#define PADW 152             // 128 + 24; ALSO the x row stride (152x152 input)
#define PADA (PADW * PADW)   // 23104

// Env tables are stored residue-split: slot(r) = (r&3)*160 + (r>>2).
// In the vectorized loops f = peel + 4k + j, so within one unrolled j-step all
// lanes share (r&3) -> LDS reads are stride-1, conflict-free (vs 8-way for a
// linear table read at lane-stride 4).
//
// d_ws layout (floats):
//   [0, 640)             LRI env (residue-split, normalized)
//   [640, 1280)          AFF env (residue-split; max is exactly 1, no norm)
//   [1280, 24384)        padded lat0, 152x152, border = 0
//   [24384, 47488)       padded latf, 152x152, border = HOMEO_TARGET
//   [47488, 51584)       per-block corr partials (4096)
#define WS_LRI 0
#define WS_AE 640
#define WS_LAT0P 1280
#define WS_LATFP 24384
#define WS_PART 47488

// floor(r/25) for r in [0,625): r*10486>>18.  Proof: 25*10486 = 2^18+6;
// r=25q+s -> r*10486 = q*2^18 + 6q + 10486s, and 6*24+10486*24 < 2^18.
__device__ __forceinline__ int div25(int r) { return (r * 10486) >> 18; }

// window offset for patch index r: ki*152 + kj = r + 127*(r/25)
__device__ __forceinline__ int woff(int r) { return r + 127 * div25(r); }

// ---------------------------------------------------------------------------
// Kernel 0 (16 blocks): block 0 builds both env tables (bit-identical values
// to the original per-block computation); all blocks fill the padded lat0
// (zeros) and latf (0.04 border) arrays.  Runs every launch (ws may be
// re-poisoned between iterations).
// ---------------------------------------------------------------------------
__global__ __launch_bounds__(256) void k_init(float* __restrict__ ws) {
    const int tid = threadIdx.x;
    if (blockIdx.x == 0) {
        __shared__ float s_tmp[640];
        __shared__ float s_red[4];
        // AFF env: cos(d*pi/25)^2 * (d < 12.5)
        for (int s = tid; s < 640; s += 256) {
            int q = s / 160;           // r & 3
            int t = s - q * 160;       // r >> 2
            int r = (t << 2) | q;
            float v = 0.0f;
            if (r < PATCH) {
                float di = (float)div25(r) - 12.0f;
                float dj = (float)(r - 25 * div25(r)) - 12.0f;
                float d = sqrtf(di * di + dj * dj);
                if (d < 12.5f) {
                    float c = cosf(d * (PI_F / 25.0f));
                    v = c * c;
                }
            }
            ws[WS_AE + s] = v;
        }
        // LRI env: cos(d*pi/25)^2 * (1-inh) * (d<12.5), normalized by max
        float m = 0.0f;
        for (int s = tid; s < 640; s += 256) {
            int q = s / 160;
            int t = s - q * 160;
            int r = (t << 2) | q;
            float v = 0.0f;
            if (r < PATCH) {
                float di = (float)div25(r) - 12.0f;
                float dj = (float)(r - 25 * div25(r)) - 12.0f;
                float d = sqrtf(di * di + dj * dj);
                if (d < 12.5f) {
                    float c1 = cosf(d * (PI_F / 25.0f));
                    float inh = 0.0f;
                    if (d < 4.5f) {
                        float c2 = cosf(d * (PI_F / 9.0f));
                        inh = c2 * c2;
                    }
                    v = c1 * c1 * (1.0f - inh);
                }
            }
            s_tmp[s] = v;
            m = fmaxf(m, v);
        }
        for (int o = 32; o; o >>= 1) m = fmaxf(m, __shfl_down(m, o));
        if (!(tid & 63)) s_red[tid >> 6] = m;
        __syncthreads();
        float inv = 1.0f / fmaxf(fmaxf(s_red[0], s_red[1]),
                                 fmaxf(s_red[2], s_red[3]));
        for (int s = tid; s < 640; s += 256) ws[WS_LRI + s] = s_tmp[s] * inv;
    }
    // all blocks: border/body fill of padded arrays (interiors overwritten
    // later in the same launch by k_aff / k_lat)
    const int gid = blockIdx.x * 256 + tid;
    const int gsz = gridDim.x * 256;
    for (int i = gid; i < 2 * PADA; i += gsz) {
        if (i < PADA) ws[WS_LAT0P + i] = 0.0f;
        else          ws[WS_LATFP + i - PADA] = 0.04f;
    }
}

// ---------------------------------------------------------------------------
// Kernel 1: raw_aff + padded lat0.  One block per l.  Pure-read kernel:
// rfs is consumed with ALIGNED float4 loads (base = l*1250; peel 2 elems when
// l is odd).  No tiles write here (that was the misaligned scalar store
// stream) -- tiles moved to its own aligned writer kernel.
// ---------------------------------------------------------------------------
__global__ __launch_bounds__(256) void k_aff(const float* __restrict__ x,
                                             const float* __restrict__ rfs,
                                             const float* __restrict__ ada,
                                             float* __restrict__ raw_aff,
                                             float* __restrict__ ws) {
    __shared__ float s_ae[640];
    __shared__ float s_part[4];
    const int tid = threadIdx.x;
    for (int i = tid; i < 640; i += 256) s_ae[i] = ws[WS_AE + i];
    __syncthreads();

    const int l = blockIdx.x;
    const int li = l >> 7;
    const int lj = l & 127;
    const int wbase = li * PADW + lj;           // x row stride is also 152
    const long base = (long)l * FEAT;
    const int peel = (l & 1) ? 2 : 0;           // (l*1250) mod 4 = 2*(l&1)

    float acc = 0.0f;
    if (tid < peel) {                            // f < 2: c=0, r=f, woff=f
        int f = tid;
        float t = x[wbase + f] * s_ae[(f & 3) * 160 + (f >> 2)];
        acc += t * fmaxf(rfs[base + f], 0.0f);
    }
    const int n4 = (FEAT - peel) >> 2;           // 312 either way
    for (int k = tid; k < n4; k += 256) {
        int f0 = peel + (k << 2);
        const float4 rv = *reinterpret_cast<const float4*>(rfs + base + f0);
#pragma unroll
        for (int j = 0; j < 4; ++j) {
            int f = f0 + j;
            int c = (f >= PATCH);
            int r = f - (c ? PATCH : 0);
            float t = x[c * PADA + wbase + woff(r)]
                      * s_ae[(r & 3) * 160 + (r >> 2)];
            acc += t * fmaxf((&rv.x)[j], 0.0f);
        }
    }
    const int tail = (FEAT - peel) & 3;          // 2 (l even) or 0
    if (tid < tail) {
        int f = peel + (n4 << 2) + tid;          // 1248/1249: c=1
        int r = f - PATCH;
        float t = x[PADA + wbase + woff(r)] * s_ae[(r & 3) * 160 + (r >> 2)];
        acc += t * fmaxf(rfs[base + f], 0.0f);
    }

    for (int o = 32; o; o >>= 1) acc += __shfl_down(acc, o);
    const int lane = tid & 63, wv = tid >> 6;
    if (!lane) s_part[wv] = acc;
    __syncthreads();
    if (!tid) {
        float ra = s_part[0] + s_part[1] + s_part[2] + s_part[3];
        raw_aff[l] = ra;
        ws[WS_LAT0P + (li + 12) * PADW + (lj + 12)] = fmaxf(ra - ada[l], 0.0f);
    }
}

// ---------------------------------------------------------------------------
// Kernel 2: tiles writer.  Flat grid-stride over all 20.48M elements with a
// GLOBAL 3-element peel: tiles = out+32769 floats, so element i is 16B-aligned
// iff i==3 (mod 4).  Every float4 store is aligned; block boundaries don't
// matter.  x is L2-resident (185 KB); this kernel is pure write-BW.
// ---------------------------------------------------------------------------
#define NTILE 20480000
#define NF4 5119999        // (NTILE - 3) / 4; tail = 1 elem
__global__ __launch_bounds__(256) void k_tiles(const float* __restrict__ x,
                                               float* __restrict__ tiles,
                                               const float* __restrict__ ws) {
    __shared__ float s_ae[640];
    const int tid = threadIdx.x;
    for (int i = tid; i < 640; i += 256) s_ae[i] = ws[WS_AE + i];
    __syncthreads();

    const int gid = blockIdx.x * 256 + tid;
    const int gsz = gridDim.x * 256;
    for (long k = gid; k < NF4; k += gsz) {
        long i0 = 3 + (k << 2);
        float4 v;
#pragma unroll
        for (int j = 0; j < 4; ++j) {
            unsigned int e = (unsigned int)(i0 + j);
            unsigned int l = e / 1250u;          // magic-div by compiler
            int f = (int)(e - l * 1250u);
            int c = (f >= PATCH);
            int r = f - (c ? PATCH : 0);
            int li = (int)(l >> 7), lj = (int)(l & 127u);
            (&v.x)[j] = x[c * PADA + li * PADW + lj + woff(r)]
                        * s_ae[(r & 3) * 160 + (r >> 2)];
        }
        *reinterpret_cast<float4*>(tiles + i0) = v;
    }
    if (blockIdx.x == 0 && tid < 4) {            // peel i=0,1,2 + tail
        unsigned int e = (tid < 3) ? (unsigned int)tid : (NTILE - 1u);
        unsigned int l = e / 1250u;
        int f = (int)(e - l * 1250u);
        int c = (f >= PATCH);
        int r = f - (c ? PATCH : 0);
        int li = (int)(l >> 7), lj = (int)(l & 127u);
        tiles[e] = x[c * PADA + li * PADW + lj + woff(r)]
                   * s_ae[(r & 3) * 160 + (r >> 2)];
    }
}

// ---------------------------------------------------------------------------
// Kernel 3: final lat.  One wave per l, 4 per block.  lw consumed with
// ALIGNED float4 loads (base = l*625; peel (4-l)&3).  lat0 gathered from the
// padded array -- no bounds branches.
// ---------------------------------------------------------------------------
__global__ __launch_bounds__(256) void k_lat(const float* __restrict__ raw_aff,
                                             const float* __restrict__ ada,
                                             const float* __restrict__ lw,
                                             float* __restrict__ latf,
                                             float* __restrict__ ws) {
    __shared__ float s_le[640];
    const int tid = threadIdx.x;
    for (int i = tid; i < 640; i += 256) s_le[i] = ws[WS_LRI + i];
    __syncthreads();

    const int lane = tid & 63, wv = tid >> 6;
    const int l = blockIdx.x * 4 + wv;
    const int li = l >> 7, lj = l & 127;
    const int wbase = li * PADW + lj;
    const long base = (long)l * PATCH;
    const float* __restrict__ plat0 = ws + WS_LAT0P;

    float acc = 0.0f;
    const int peel = (4 - (l & 3)) & 3;          // (l*625) mod 4 = l mod 4
    if (lane < peel) {                            // f<3: woff(f)=f
        int f = lane;
        acc += plat0[wbase + f] * s_le[(f & 3) * 160 + (f >> 2)]
               * fmaxf(lw[base + f], 0.0f);
    }
    const int n4 = (PATCH - peel) >> 2;
    for (int k = lane; k < n4; k += 64) {
        int f0 = peel + (k << 2);
        const float4 w4 = *reinterpret_cast<const float4*>(lw + base + f0);
#pragma unroll
        for (int j = 0; j < 4; ++j) {
            int f = f0 + j;
            acc += plat0[wbase + woff(f)] * s_le[(f & 3) * 160 + (f >> 2)]
                   * fmaxf((&w4.x)[j], 0.0f);
        }
    }
    const int tail = (PATCH - peel) & 3;
    if (lane < tail) {
        int f = peel + (n4 << 2) + lane;
        acc += plat0[wbase + woff(f)] * s_le[(f & 3) * 160 + (f >> 2)]
               * fmaxf(lw[base + f], 0.0f);
    }
    for (int o = 32; o; o >>= 1) acc += __shfl_down(acc, o);

    if (!lane) {
        float aff_l = raw_aff[l] - ada[l];
        float lat0_l = fmaxf(aff_l, 0.0f);
        float v = (lat0_l - acc) /* *STRENGTH=1 */ + aff_l;
        float lv = tanhf(fmaxf(v, 0.0f));
        latf[l] = lv;
        ws[WS_LATFP + (li + 12) * PADW + (lj + 12)] = lv;
    }
}

// ---------------------------------------------------------------------------
// Kernel 4: corr partials.  Same structure as k_lat; gathers the padded latf
// (border = 0.04 = HOMEO_TARGET from k_init).
// ---------------------------------------------------------------------------
__global__ __launch_bounds__(256) void k_corr(const float* __restrict__ latf,
                                              const float* __restrict__ lw,
                                              float* __restrict__ ws) {
    __shared__ float s_le[640];
    __shared__ float s_part[4];
    const int tid = threadIdx.x;
    for (int i = tid; i < 640; i += 256) s_le[i] = ws[WS_LRI + i];
    __syncthreads();

    const int lane = tid & 63, wv = tid >> 6;
    const int l = blockIdx.x * 4 + wv;
    const int li = l >> 7, lj = l & 127;
    const int wbase = li * PADW + lj;
    const long base = (long)l * PATCH;
    const float* __restrict__ platf = ws + WS_LATFP;

    float acc = 0.0f;
    const int peel = (4 - (l & 3)) & 3;
    if (lane < peel) {
        int f = lane;
        acc += platf[wbase + f] * s_le[(f & 3) * 160 + (f >> 2)]
               * fmaxf(lw[base + f], 0.0f);
    }
    const int n4 = (PATCH - peel) >> 2;
    for (int k = lane; k < n4; k += 64) {
        int f0 = peel + (k << 2);
        const float4 w4 = *reinterpret_cast<const float4*>(lw + base + f0);
#pragma unroll
        for (int j = 0; j < 4; ++j) {
            int f = f0 + j;
            acc += platf[wbase + woff(f)] * s_le[(f & 3) * 160 + (f >> 2)]
                   * fmaxf((&w4.x)[j], 0.0f);
        }
    }
    const int tail = (PATCH - peel) & 3;
    if (lane < tail) {
        int f = peel + (n4 << 2) + lane;
        acc += platf[wbase + woff(f)] * s_le[(f & 3) * 160 + (f >> 2)]
               * fmaxf(lw[base + f], 0.0f);
    }
    for (int o = 32; o; o >>= 1) acc += __shfl_down(acc, o);

    if (!lane) s_part[wv] = acc * latf[l];
    __syncthreads();
    if (!tid)
        ws[WS_PART + blockIdx.x] = s_part[0] + s_part[1] + s_part[2] + s_part[3];
}

// ---------------------------------------------------------------------------
// Kernel 5: deterministic sum of 4096 partials -> corr scalar.
// ---------------------------------------------------------------------------
__global__ __launch_bounds__(256) void k_reduce(const float* __restrict__ ws,
                                                float* __restrict__ corr) {
    __shared__ float s_part[4];
    const int tid = threadIdx.x;
    const int lane = tid & 63, wv = tid >> 6;
    float acc = 0.0f;
    for (int i = tid; i < 4096; i += 256) acc += ws[WS_PART + i];
    for (int o = 32; o; o >>= 1) acc += __shfl_down(acc, o);
    if (!lane) s_part[wv] = acc;
    __syncthreads();
    if (!tid) corr[0] = s_part[0] + s_part[1] + s_part[2] + s_part[3];
}

// ---------------------------------------------------------------------------
// d_out layout (flat, return order):
//   [0, 16384)              raw_aff   [1,1,128,128]
//   [16384, 32768)          lat       [1,1,128,128]
//   [32768]                 lat_correlations (scalar)
//   [32769, 32769+20480000) tiles     [16384, 1, 1250]
// ---------------------------------------------------------------------------
extern "C" void kernel_launch(void* const* d_in, const int* in_sizes, int n_in,
                              void* d_out, int out_size, void* d_ws, size_t ws_size,
                              hipStream_t stream) {
    const float* x   = (const float*)d_in[0];   // [1,2,152,152]
    const float* rfs = (const float*)d_in[1];   // [16384,1250,1]
    const float* lw  = (const float*)d_in[2];   // [16384,625,1]
    const float* ada = (const float*)d_in[3];   // [1,1,128,128]

    float* out      = (float*)d_out;
    float* raw_aff  = out;
    float* latf     = out + S * S;
    float* corr     = out + 2 * S * S;
    float* tiles    = out + 2 * S * S + 1;
    float* ws       = (float*)d_ws;

    k_init<<<16, 256, 0, stream>>>(ws);
    k_aff<<<S * S, 256, 0, stream>>>(x, rfs, ada, raw_aff, ws);
    k_tiles<<<4096, 256, 0, stream>>>(x, tiles, ws);
    k_lat<<<(S * S) / 4, 256, 0, stream>>>(raw_aff, ada, lw, latf, ws);
    k_corr<<<(S * S) / 4, 256, 0, stream>>>(latf, lw, ws);
    k_reduce<<<1, 256, 0, stream>>>(ws, corr);
}

// Round 3
// 232.544 us; speedup vs baseline: 1.0505x; 1.0505x over previous
//
#include <hip/hip_runtime.h>
#include <math.h>

#define S 128
#define KA 25
#define KL 25
#define PATCH 625
#define FEAT 1250
#define PI_F 3.14159265358979323846f
#define PADW 152             // 128 + 24; ALSO the x row stride (152x152 input)
#define PADA (PADW * PADW)   // 23104

// Env tables are stored residue-split: slot(r) = (r&3)*160 + (r>>2).
// In the vectorized loops f = peel + 4k + j, so within one unrolled j-step all
// lanes share (r&3) -> LDS reads are stride-1, conflict-free.
//
// d_ws layout (floats):
//   [0, 640)             LRI env (residue-split, normalized)
//   [640, 1280)          AFF env (residue-split; max is exactly 1, no norm)
//   [1280, 24384)        padded lat0, 152x152, border = 0
//   [24384, 47488)       padded latf, 152x152, border = HOMEO_TARGET
//   [47488, 49536)       per-block corr partials (2048)
#define WS_LRI 0
#define WS_AE 640
#define WS_LAT0P 1280
#define WS_LATFP 24384
#define WS_PART 47488
#define NPART 2048

// floor(r/25) for r in [0,625): r*10486>>18.  Proof: 25*10486 = 2^18+6;
// r=25q+s -> r*10486 = q*2^18 + 6q + 10486s, and 6*24+10486*24 < 2^18.
__device__ __forceinline__ int div25(int r) { return (r * 10486) >> 18; }

// window offset for patch index r: ki*152 + kj = r + 127*(r/25)
__device__ __forceinline__ int woff(int r) { return r + 127 * div25(r); }

// ---------------------------------------------------------------------------
// Kernel 0 (16 blocks): block 0 builds both env tables (bit-identical values
// to the original per-block computation); all blocks fill the padded lat0
// (zeros) and latf (0.04 border) arrays.  Runs every launch.
// ---------------------------------------------------------------------------
__global__ __launch_bounds__(256) void k_init(float* __restrict__ ws) {
    const int tid = threadIdx.x;
    if (blockIdx.x == 0) {
        __shared__ float s_tmp[640];
        __shared__ float s_red[4];
        for (int s = tid; s < 640; s += 256) {     // AFF env
            int q = s / 160;           // r & 3
            int t = s - q * 160;       // r >> 2
            int r = (t << 2) | q;
            float v = 0.0f;
            if (r < PATCH) {
                float di = (float)div25(r) - 12.0f;
                float dj = (float)(r - 25 * div25(r)) - 12.0f;
                float d = sqrtf(di * di + dj * dj);
                if (d < 12.5f) {
                    float c = cosf(d * (PI_F / 25.0f));
                    v = c * c;
                }
            }
            ws[WS_AE + s] = v;
        }
        float m = 0.0f;
        for (int s = tid; s < 640; s += 256) {     // LRI env
            int q = s / 160;
            int t = s - q * 160;
            int r = (t << 2) | q;
            float v = 0.0f;
            if (r < PATCH) {
                float di = (float)div25(r) - 12.0f;
                float dj = (float)(r - 25 * div25(r)) - 12.0f;
                float d = sqrtf(di * di + dj * dj);
                if (d < 12.5f) {
                    float c1 = cosf(d * (PI_F / 25.0f));
                    float inh = 0.0f;
                    if (d < 4.5f) {
                        float c2 = cosf(d * (PI_F / 9.0f));
                        inh = c2 * c2;
                    }
                    v = c1 * c1 * (1.0f - inh);
                }
            }
            s_tmp[s] = v;
            m = fmaxf(m, v);
        }
        for (int o = 32; o; o >>= 1) m = fmaxf(m, __shfl_down(m, o));
        if (!(tid & 63)) s_red[tid >> 6] = m;
        __syncthreads();
        float inv = 1.0f / fmaxf(fmaxf(s_red[0], s_red[1]),
                                 fmaxf(s_red[2], s_red[3]));
        for (int s = tid; s < 640; s += 256) ws[WS_LRI + s] = s_tmp[s] * inv;
    }
    const int gid = blockIdx.x * 256 + tid;
    const int gsz = gridDim.x * 256;
    for (int i = gid; i < 2 * PADA; i += gsz) {
        if (i < PADA) ws[WS_LAT0P + i] = 0.0f;
        else          ws[WS_LATFP + i - PADA] = 0.04f;
    }
}

// ---------------------------------------------------------------------------
// Kernel 1: raw_aff + padded lat0.  FAT kernel: 2048 blocks, env staged to
// LDS once per block, then each WAVE owns a row l (grid-stride, 2 rows/wave)
// with zero further barriers.  Previous structure (16384 tiny blocks, 2
// barriers + cross-wave reduce each, ~5 elem/thread) was block-overhead-bound
// at ~49 us regardless of load vectorization.
// rfs rows are consumed with ALIGNED float4 loads (base = l*1250; peel 2
// when l odd).
// ---------------------------------------------------------------------------
__global__ __launch_bounds__(256) void k_aff(const float* __restrict__ x,
                                             const float* __restrict__ rfs,
                                             const float* __restrict__ ada,
                                             float* __restrict__ raw_aff,
                                             float* __restrict__ ws) {
    __shared__ float s_ae[640];
    const int tid = threadIdx.x;
    for (int i = tid; i < 640; i += 256) s_ae[i] = ws[WS_AE + i];
    __syncthreads();

    const int lane = tid & 63;
    const int wid = blockIdx.x * 4 + (tid >> 6);   // 8192 waves

    for (int l = wid; l < S * S; l += 8192) {
        const int li = l >> 7, lj = l & 127;
        const int wbase = li * PADW + lj;          // x row stride is also 152
        const long base = (long)l * FEAT;
        const int peel = (l & 1) ? 2 : 0;          // (l*1250) mod 4 = 2*(l&1)

        float acc = 0.0f;
        if (lane < peel) {                          // f < 2: c=0, woff(f)=f
            int f = lane;
            float t = x[wbase + f] * s_ae[(f & 3) * 160 + (f >> 2)];
            acc += t * fmaxf(rfs[base + f], 0.0f);
        }
        const int n4 = (FEAT - peel) >> 2;          // 312 either way
        for (int k = lane; k < n4; k += 64) {
            int f0 = peel + (k << 2);
            const float4 rv = *reinterpret_cast<const float4*>(rfs + base + f0);
#pragma unroll
            for (int j = 0; j < 4; ++j) {
                int f = f0 + j;
                int c = (f >= PATCH);
                int r = f - (c ? PATCH : 0);
                float t = x[c * PADA + wbase + woff(r)]
                          * s_ae[(r & 3) * 160 + (r >> 2)];
                acc += t * fmaxf((&rv.x)[j], 0.0f);
            }
        }
        const int tail = (FEAT - peel) & 3;         // 2 (l even) or 0
        if (lane < tail) {
            int f = peel + (n4 << 2) + lane;        // 1248/1249: c=1
            int r = f - PATCH;
            float t = x[PADA + wbase + woff(r)] * s_ae[(r & 3) * 160 + (r >> 2)];
            acc += t * fmaxf(rfs[base + f], 0.0f);
        }

        for (int o = 32; o; o >>= 1) acc += __shfl_down(acc, o);
        if (!lane) {
            raw_aff[l] = acc;
            ws[WS_LAT0P + (li + 12) * PADW + (lj + 12)] =
                fmaxf(acc - ada[l], 0.0f);
        }
    }
}

// ---------------------------------------------------------------------------
// Kernel 2: tiles writer.  Flat grid-stride over all 20.48M elements with a
// GLOBAL 3-element peel: tiles = out+32769 floats, so element i is 16B-aligned
// iff i==3 (mod 4).  Every float4 store is aligned.  x is L2-resident.
// ---------------------------------------------------------------------------
#define NTILE 20480000
#define NF4 5119999        // (NTILE - 3) / 4; tail = 1 elem
__global__ __launch_bounds__(256) void k_tiles(const float* __restrict__ x,
                                               float* __restrict__ tiles,
                                               const float* __restrict__ ws) {
    __shared__ float s_ae[640];
    const int tid = threadIdx.x;
    for (int i = tid; i < 640; i += 256) s_ae[i] = ws[WS_AE + i];
    __syncthreads();

    const int gid = blockIdx.x * 256 + tid;
    const int gsz = gridDim.x * 256;
    for (long k = gid; k < NF4; k += gsz) {
        long i0 = 3 + (k << 2);
        float4 v;
#pragma unroll
        for (int j = 0; j < 4; ++j) {
            unsigned int e = (unsigned int)(i0 + j);
            unsigned int l = e / 1250u;          // magic-div by compiler
            int f = (int)(e - l * 1250u);
            int c = (f >= PATCH);
            int r = f - (c ? PATCH : 0);
            int li = (int)(l >> 7), lj = (int)(l & 127u);
            (&v.x)[j] = x[c * PADA + li * PADW + lj + woff(r)]
                        * s_ae[(r & 3) * 160 + (r >> 2)];
        }
        *reinterpret_cast<float4*>(tiles + i0) = v;
    }
    if (blockIdx.x == 0 && tid < 4) {            // peel i=0,1,2 + tail
        unsigned int e = (tid < 3) ? (unsigned int)tid : (NTILE - 1u);
        unsigned int l = e / 1250u;
        int f = (int)(e - l * 1250u);
        int c = (f >= PATCH);
        int r = f - (c ? PATCH : 0);
        int li = (int)(l >> 7), lj = (int)(l & 127u);
        tiles[e] = x[c * PADA + li * PADW + lj + woff(r)]
                   * s_ae[(r & 3) * 160 + (r >> 2)];
    }
}

// ---------------------------------------------------------------------------
// Kernel 3: final lat.  FAT kernel: 2048 blocks, env once per block, wave
// owns row l (grid-stride, 2 rows/wave).  lw consumed with ALIGNED float4
// loads (base = l*625; peel (4-l)&3).  lat0 gathered from padded array (L2).
// ---------------------------------------------------------------------------
__global__ __launch_bounds__(256) void k_lat(const float* __restrict__ raw_aff,
                                             const float* __restrict__ ada,
                                             const float* __restrict__ lw,
                                             float* __restrict__ latf,
                                             float* __restrict__ ws) {
    __shared__ float s_le[640];
    const int tid = threadIdx.x;
    for (int i = tid; i < 640; i += 256) s_le[i] = ws[WS_LRI + i];
    __syncthreads();

    const int lane = tid & 63;
    const int wid = blockIdx.x * 4 + (tid >> 6);
    const float* __restrict__ plat0 = ws + WS_LAT0P;

    for (int l = wid; l < S * S; l += 8192) {
        const int li = l >> 7, lj = l & 127;
        const int wbase = li * PADW + lj;
        const long base = (long)l * PATCH;

        float acc = 0.0f;
        const int peel = (4 - (l & 3)) & 3;        // (l*625) mod 4 = l mod 4
        if (lane < peel) {                          // f<3: woff(f)=f
            int f = lane;
            acc += plat0[wbase + f] * s_le[(f & 3) * 160 + (f >> 2)]
                   * fmaxf(lw[base + f], 0.0f);
        }
        const int n4 = (PATCH - peel) >> 2;
        for (int k = lane; k < n4; k += 64) {
            int f0 = peel + (k << 2);
            const float4 w4 = *reinterpret_cast<const float4*>(lw + base + f0);
#pragma unroll
            for (int j = 0; j < 4; ++j) {
                int f = f0 + j;
                acc += plat0[wbase + woff(f)] * s_le[(f & 3) * 160 + (f >> 2)]
                       * fmaxf((&w4.x)[j], 0.0f);
            }
        }
        const int tail = (PATCH - peel) & 3;
        if (lane < tail) {
            int f = peel + (n4 << 2) + lane;
            acc += plat0[wbase + woff(f)] * s_le[(f & 3) * 160 + (f >> 2)]
                   * fmaxf(lw[base + f], 0.0f);
        }
        for (int o = 32; o; o >>= 1) acc += __shfl_down(acc, o);

        if (!lane) {
            float aff_l = raw_aff[l] - ada[l];
            float lat0_l = fmaxf(aff_l, 0.0f);
            float v = (lat0_l - acc) /* *STRENGTH=1 */ + aff_l;
            float lv = tanhf(fmaxf(v, 0.0f));
            latf[l] = lv;
            ws[WS_LATFP + (li + 12) * PADW + (lj + 12)] = lv;
        }
    }
}

// ---------------------------------------------------------------------------
// Kernel 4: corr partials.  Same fat structure; gathers padded latf
// (border = 0.04 = HOMEO_TARGET from k_init).  One partial per block.
// ---------------------------------------------------------------------------
__global__ __launch_bounds__(256) void k_corr(const float* __restrict__ latf,
                                              const float* __restrict__ lw,
                                              float* __restrict__ ws) {
    __shared__ float s_le[640];
    __shared__ float s_part[4];
    const int tid = threadIdx.x;
    for (int i = tid; i < 640; i += 256) s_le[i] = ws[WS_LRI + i];
    __syncthreads();

    const int lane = tid & 63, wv = tid >> 6;
    const int wid = blockIdx.x * 4 + wv;
    const float* __restrict__ platf = ws + WS_LATFP;

    float wsum = 0.0f;
    for (int l = wid; l < S * S; l += 8192) {
        const int li = l >> 7, lj = l & 127;
        const int wbase = li * PADW + lj;
        const long base = (long)l * PATCH;

        float acc = 0.0f;
        const int peel = (4 - (l & 3)) & 3;
        if (lane < peel) {
            int f = lane;
            acc += platf[wbase + f] * s_le[(f & 3) * 160 + (f >> 2)]
                   * fmaxf(lw[base + f], 0.0f);
        }
        const int n4 = (PATCH - peel) >> 2;
        for (int k = lane; k < n4; k += 64) {
            int f0 = peel + (k << 2);
            const float4 w4 = *reinterpret_cast<const float4*>(lw + base + f0);
#pragma unroll
            for (int j = 0; j < 4; ++j) {
                int f = f0 + j;
                acc += platf[wbase + woff(f)] * s_le[(f & 3) * 160 + (f >> 2)]
                       * fmaxf((&w4.x)[j], 0.0f);
            }
        }
        const int tail = (PATCH - peel) & 3;
        if (lane < tail) {
            int f = peel + (n4 << 2) + lane;
            acc += platf[wbase + woff(f)] * s_le[(f & 3) * 160 + (f >> 2)]
                   * fmaxf(lw[base + f], 0.0f);
        }
        for (int o = 32; o; o >>= 1) acc += __shfl_down(acc, o);
        if (!lane) wsum += acc * latf[l];
    }
    if (!lane) s_part[wv] = wsum;
    __syncthreads();
    if (!tid)
        ws[WS_PART + blockIdx.x] = s_part[0] + s_part[1] + s_part[2] + s_part[3];
}

// ---------------------------------------------------------------------------
// Kernel 5: deterministic sum of 2048 partials -> corr scalar.
// ---------------------------------------------------------------------------
__global__ __launch_bounds__(256) void k_reduce(const float* __restrict__ ws,
                                                float* __restrict__ corr) {
    __shared__ float s_part[4];
    const int tid = threadIdx.x;
    const int lane = tid & 63, wv = tid >> 6;
    float acc = 0.0f;
    for (int i = tid; i < NPART; i += 256) acc += ws[WS_PART + i];
    for (int o = 32; o; o >>= 1) acc += __shfl_down(acc, o);
    if (!lane) s_part[wv] = acc;
    __syncthreads();
    if (!tid) corr[0] = s_part[0] + s_part[1] + s_part[2] + s_part[3];
}

// ---------------------------------------------------------------------------
// d_out layout (flat, return order):
//   [0, 16384)              raw_aff   [1,1,128,128]
//   [16384, 32768)          lat       [1,1,128,128]
//   [32768]                 lat_correlations (scalar)
//   [32769, 32769+20480000) tiles     [16384, 1, 1250]
// ---------------------------------------------------------------------------
extern "C" void kernel_launch(void* const* d_in, const int* in_sizes, int n_in,
                              void* d_out, int out_size, void* d_ws, size_t ws_size,
                              hipStream_t stream) {
    const float* x   = (const float*)d_in[0];   // [1,2,152,152]
    const float* rfs = (const float*)d_in[1];   // [16384,1250,1]
    const float* lw  = (const float*)d_in[2];   // [16384,625,1]
    const float* ada = (const float*)d_in[3];   // [1,1,128,128]

    float* out      = (float*)d_out;
    float* raw_aff  = out;
    float* latf     = out + S * S;
    float* corr     = out + 2 * S * S;
    float* tiles    = out + 2 * S * S + 1;
    float* ws       = (float*)d_ws;

    k_init<<<16, 256, 0, stream>>>(ws);
    k_aff<<<2048, 256, 0, stream>>>(x, rfs, ada, raw_aff, ws);
    k_tiles<<<2048, 256, 0, stream>>>(x, tiles, ws);
    k_lat<<<2048, 256, 0, stream>>>(raw_aff, ada, lw, latf, ws);
    k_corr<<<2048, 256, 0, stream>>>(latf, lw, ws);
    k_reduce<<<1, 256, 0, stream>>>(ws, corr);
}